// Round 1
// baseline (105.000 us; speedup 1.0000x reference)
//
#include <hip/hip_runtime.h>

#define FTN 8
#define SEG 128
#define DIM 1024
#define BLK 256   // 1024 elems / 4-per-thread

// One block per row of x [B, 1024].
// Thread t owns elements [4t, 4t+4) -- all within segment (t>>5).
__global__ __launch_bounds__(BLK)
void il_kernel(const float* __restrict__ x,
               const float* __restrict__ W,
               const float* __restrict__ b,
               float* __restrict__ out) {
    __shared__ float sW[FTN * FTN];
    __shared__ float sb[FTN];
    __shared__ float smax[FTN];

    const int row = blockIdx.x;
    const int t   = threadIdx.x;

    if (t < FTN * FTN) sW[t] = W[t];
    if (t < FTN)       sb[t] = b[t];

    const float4* xr = reinterpret_cast<const float4*>(x + (size_t)row * DIM);
    float4 v = xr[t];

    // local max of 4 elems, then reduce across the 32-lane segment group.
    float m = fmaxf(fmaxf(v.x, v.y), fmaxf(v.z, v.w));
    #pragma unroll
    for (int off = 1; off < 32; off <<= 1)
        m = fmaxf(m, __shfl_xor(m, off));

    const int seg = t >> 5;           // 8 segments, 32 threads each
    if ((t & 31) == 0) smax[seg] = m;
    __syncthreads();

    // gate for this thread's segment: sigmoid( W[seg,:] . smax + b[seg] )
    float z = sb[seg];
    #pragma unroll
    for (int j = 0; j < FTN; ++j)
        z = fmaf(sW[seg * FTN + j], smax[j], z);
    const float scale = 1.0f / (1.0f + __expf(-z));
    const float g = 1.0f + scale;     // out = x + x*scale

    float4 o;
    o.x = v.x * g;
    o.y = v.y * g;
    o.z = v.z * g;
    o.w = v.w * g;
    reinterpret_cast<float4*>(out + (size_t)row * DIM)[t] = o;
}

extern "C" void kernel_launch(void* const* d_in, const int* in_sizes, int n_in,
                              void* d_out, int out_size, void* d_ws, size_t ws_size,
                              hipStream_t stream) {
    const float* x = (const float*)d_in[0];
    const float* W = (const float*)d_in[1];
    const float* b = (const float*)d_in[2];
    float* out = (float*)d_out;
    const int B = in_sizes[0] / DIM;   // 65536
    il_kernel<<<B, BLK, 0, stream>>>(x, W, b, out);
}

// Round 2
// 101.359 us; speedup vs baseline: 1.0359x; 1.0359x over previous
//
#include <hip/hip_runtime.h>

#define DIM 1024
#define BLK 256
#define GRID 2048   // 2048 blocks * 4 waves = 8192 waves; 65536 rows -> 8 rows/wave

// One wave (64 lanes) per row. Lane l, load k covers elements [256k + 4l, 256k+4l+4):
//   lanes 0..31  -> segment 2k
//   lanes 32..63 -> segment 2k+1
// 32-lane xor-reduce gives each half its segment max; shfl_xor(.,32) fetches the
// sibling segment's max, so every lane holds all 8 maxes in registers.
__global__ __launch_bounds__(BLK)
void il_kernel(const float* __restrict__ x,
               const float* __restrict__ W,
               const float* __restrict__ b,
               float* __restrict__ out, int B) {
    const int lane = threadIdx.x & 63;
    const int half = lane >> 5;                       // 0 or 1
    const int gw   = blockIdx.x * (BLK / 64) + (threadIdx.x >> 6);
    const int nw   = GRID * (BLK / 64);

    // Hoist gate params for this lane's 4 segments (2k + half) into registers.
    float wreg[4][8], breg[4];
    #pragma unroll
    for (int k = 0; k < 4; ++k) {
        const int s = 2 * k + half;
        breg[k] = b[s];
        #pragma unroll
        for (int j = 0; j < 8; ++j) wreg[k][j] = W[s * 8 + j];
    }

    for (int row = gw; row < B; row += nw) {
        const float4* xr = reinterpret_cast<const float4*>(x + (size_t)row * DIM);
        float4* orow     = reinterpret_cast<float4*>(out + (size_t)row * DIM);

        float4 v[4];
        #pragma unroll
        for (int k = 0; k < 4; ++k) v[k] = xr[lane + 64 * k];   // 4 independent loads

        float m[4], n[4];
        #pragma unroll
        for (int k = 0; k < 4; ++k) {
            float mm = fmaxf(fmaxf(v[k].x, v[k].y), fmaxf(v[k].z, v[k].w));
            #pragma unroll
            for (int off = 1; off < 32; off <<= 1)
                mm = fmaxf(mm, __shfl_xor(mm, off));   // reduce within 32-lane half
            m[k] = mm;                                  // max of segment 2k+half
            n[k] = __shfl_xor(mm, 32);                  // max of segment 2k+(1-half)
        }

        // Assemble all 8 segment maxes (static indices after unroll -> registers).
        float smax[8];
        #pragma unroll
        for (int k = 0; k < 4; ++k) {
            smax[2 * k]     = half ? n[k] : m[k];
            smax[2 * k + 1] = half ? m[k] : n[k];
        }

        #pragma unroll
        for (int k = 0; k < 4; ++k) {
            float z = breg[k];
            #pragma unroll
            for (int j = 0; j < 8; ++j) z = fmaf(wreg[k][j], smax[j], z);
            const float g = 1.0f + 1.0f / (1.0f + __expf(-z));   // 1 + sigmoid
            float4 o;
            o.x = v[k].x * g; o.y = v[k].y * g;
            o.z = v[k].z * g; o.w = v[k].w * g;
            orow[lane + 64 * k] = o;
        }
    }
}

extern "C" void kernel_launch(void* const* d_in, const int* in_sizes, int n_in,
                              void* d_out, int out_size, void* d_ws, size_t ws_size,
                              hipStream_t stream) {
    const float* x = (const float*)d_in[0];
    const float* W = (const float*)d_in[1];
    const float* b = (const float*)d_in[2];
    float* out = (float*)d_out;
    const int B = in_sizes[0] / DIM;   // 65536
    il_kernel<<<GRID, BLK, 0, stream>>>(x, W, b, out, B);
}

// Round 3
// 101.173 us; speedup vs baseline: 1.0378x; 1.0018x over previous
//
#include <hip/hip_runtime.h>

#define DIM 1024
#define BLK 256
#define GRID 2048   // 2048 blocks * 4 waves = 8192 waves; 65536 rows -> 8 rows/wave

// One wave (64 lanes) per row. Lane l, load k covers elements [256k + 4l, 256k+4l+4):
//   lanes 0..31  -> segment 2k,  lanes 32..63 -> segment 2k+1.
// Gate MLP: lane l computes z for segment (l&7) only (8 FMAs + 1 exp), then the
// 4 gates each lane needs are pulled with __shfl broadcasts. Keeps VGPR <= 64
// so all 8 waves/SIMD stay resident (launch_bounds enforces it).
__global__ __launch_bounds__(BLK, 8)
void il_kernel(const float* __restrict__ x,
               const float* __restrict__ W,
               const float* __restrict__ b,
               float* __restrict__ out, int B) {
    const int lane = threadIdx.x & 63;
    const int half = lane >> 5;                       // 0 or 1
    const int myseg = lane & 7;                       // segment this lane gates
    const int gw   = blockIdx.x * (BLK / 64) + (threadIdx.x >> 6);
    const int nw   = GRID * (BLK / 64);

    // 8 W coefficients + 1 bias per lane (for segment myseg).
    float wreg[8];
    #pragma unroll
    for (int j = 0; j < 8; ++j) wreg[j] = W[myseg * 8 + j];
    const float breg = b[myseg];

    for (int row = gw; row < B; row += nw) {
        const float4* xr = reinterpret_cast<const float4*>(x + (size_t)row * DIM);
        float4* orow     = reinterpret_cast<float4*>(out + (size_t)row * DIM);

        float4 v[4];
        #pragma unroll
        for (int k = 0; k < 4; ++k) v[k] = xr[lane + 64 * k];   // 4 independent loads

        float smax[8];
        #pragma unroll
        for (int k = 0; k < 4; ++k) {
            float mm = fmaxf(fmaxf(v[k].x, v[k].y), fmaxf(v[k].z, v[k].w));
            #pragma unroll
            for (int off = 1; off < 32; off <<= 1)
                mm = fmaxf(mm, __shfl_xor(mm, off));   // reduce within 32-lane half
            const float nn = __shfl_xor(mm, 32);       // sibling segment's max
            smax[2 * k]     = half ? nn : mm;
            smax[2 * k + 1] = half ? mm : nn;
        }

        // One gate per lane (segment myseg), then broadcast the 4 needed ones.
        float z = breg;
        #pragma unroll
        for (int j = 0; j < 8; ++j) z = fmaf(wreg[j], smax[j], z);
        const float gg = 1.0f + 1.0f / (1.0f + __expf(-z));     // 1 + sigmoid

        #pragma unroll
        for (int k = 0; k < 4; ++k) {
            const float g = __shfl(gg, 2 * k + half);  // gate of segment 2k+half
            float4 o;
            o.x = v[k].x * g; o.y = v[k].y * g;
            o.z = v[k].z * g; o.w = v[k].w * g;
            orow[lane + 64 * k] = o;
        }
    }
}

extern "C" void kernel_launch(void* const* d_in, const int* in_sizes, int n_in,
                              void* d_out, int out_size, void* d_ws, size_t ws_size,
                              hipStream_t stream) {
    const float* x = (const float*)d_in[0];
    const float* W = (const float*)d_in[1];
    const float* b = (const float*)d_in[2];
    float* out = (float*)d_out;
    const int B = in_sizes[0] / DIM;   // 65536
    il_kernel<<<GRID, BLK, 0, stream>>>(x, W, b, out, B);
}

// Round 5
// 83.349 us; speedup vs baseline: 1.2598x; 1.2138x over previous
//
#include <hip/hip_runtime.h>

#define DIM 1024
#define BLK 256
#define GRID 2048   // 2048 blocks * 4 waves = 8192 waves; 65536 rows -> 8 rows/wave

typedef float f32x4 __attribute__((ext_vector_type(4)));   // clang vector: OK for nontemporal builtins

// One wave (64 lanes) per row; two rows in flight per loop iteration.
// Lane l, load k covers elements [256k+4l, +4): lanes 0..31 -> segment 2k,
// lanes 32..63 -> segment 2k+1. Gate MLP: lane l computes z for segment (l&7)
// only, then the 4 gates each lane needs are pulled with __shfl broadcasts.
// Output uses nontemporal stores so the write stream doesn't evict the input
// stream from L2/L3 (in+out = 512MB vs 256MB Infinity Cache).
__global__ __launch_bounds__(BLK)
void il_kernel(const float* __restrict__ x,
               const float* __restrict__ W,
               const float* __restrict__ b,
               float* __restrict__ out, int B) {
    const int lane  = threadIdx.x & 63;
    const int half  = lane >> 5;                      // 0 or 1
    const int myseg = lane & 7;                       // segment this lane gates
    const int gw    = blockIdx.x * (BLK / 64) + (threadIdx.x >> 6);
    const int nw    = GRID * (BLK / 64);

    float wreg[8];
    #pragma unroll
    for (int j = 0; j < 8; ++j) wreg[j] = W[myseg * 8 + j];
    const float breg = b[myseg];

    for (int r = gw; r < B; r += 2 * nw) {
        const int r0 = r;
        const int r1 = r + nw;
        const bool have1 = (r1 < B);

        const f32x4* xr0 = reinterpret_cast<const f32x4*>(x + (size_t)r0 * DIM);
        const f32x4* xr1 = reinterpret_cast<const f32x4*>(x + (size_t)r1 * DIM);

        f32x4 v0[4], v1[4];
        #pragma unroll
        for (int k = 0; k < 4; ++k) v0[k] = xr0[lane + 64 * k];
        if (have1) {
            #pragma unroll
            for (int k = 0; k < 4; ++k) v1[k] = xr1[lane + 64 * k];
        }

        // ---- row 0 ----
        {
            float smax[8];
            #pragma unroll
            for (int k = 0; k < 4; ++k) {
                float mm = fmaxf(fmaxf(v0[k].x, v0[k].y), fmaxf(v0[k].z, v0[k].w));
                #pragma unroll
                for (int off = 1; off < 32; off <<= 1)
                    mm = fmaxf(mm, __shfl_xor(mm, off));
                const float nn = __shfl_xor(mm, 32);
                smax[2 * k]     = half ? nn : mm;
                smax[2 * k + 1] = half ? mm : nn;
            }
            float z = breg;
            #pragma unroll
            for (int j = 0; j < 8; ++j) z = fmaf(wreg[j], smax[j], z);
            const float gg = 1.0f + 1.0f / (1.0f + __expf(-z));
            f32x4* orow = reinterpret_cast<f32x4*>(out + (size_t)r0 * DIM);
            #pragma unroll
            for (int k = 0; k < 4; ++k) {
                const float g = __shfl(gg, 2 * k + half);
                f32x4 o = v0[k] * g;
                __builtin_nontemporal_store(o, &orow[lane + 64 * k]);
            }
        }

        // ---- row 1 ----
        if (have1) {
            float smax[8];
            #pragma unroll
            for (int k = 0; k < 4; ++k) {
                float mm = fmaxf(fmaxf(v1[k].x, v1[k].y), fmaxf(v1[k].z, v1[k].w));
                #pragma unroll
                for (int off = 1; off < 32; off <<= 1)
                    mm = fmaxf(mm, __shfl_xor(mm, off));
                const float nn = __shfl_xor(mm, 32);
                smax[2 * k]     = half ? nn : mm;
                smax[2 * k + 1] = half ? mm : nn;
            }
            float z = breg;
            #pragma unroll
            for (int j = 0; j < 8; ++j) z = fmaf(wreg[j], smax[j], z);
            const float gg = 1.0f + 1.0f / (1.0f + __expf(-z));
            f32x4* orow = reinterpret_cast<f32x4*>(out + (size_t)r1 * DIM);
            #pragma unroll
            for (int k = 0; k < 4; ++k) {
                const float g = __shfl(gg, 2 * k + half);
                f32x4 o = v1[k] * g;
                __builtin_nontemporal_store(o, &orow[lane + 64 * k]);
            }
        }
    }
}

extern "C" void kernel_launch(void* const* d_in, const int* in_sizes, int n_in,
                              void* d_out, int out_size, void* d_ws, size_t ws_size,
                              hipStream_t stream) {
    const float* x = (const float*)d_in[0];
    const float* W = (const float*)d_in[1];
    const float* b = (const float*)d_in[2];
    float* out = (float*)d_out;
    const int B = in_sizes[0] / DIM;   // 65536
    il_kernel<<<GRID, BLK, 0, stream>>>(x, W, b, out, B);
}